// Round 8
// baseline (12458.244 us; speedup 1.0000x reference)
//
#include <hip/hip_runtime.h>
#include <stdint.h>

// ---------------------------------------------------------------------------
// Persistent-RNN 2-layer LSTM decoder (B=64,H=1024,OUT=512,SEQ=256), MI355X.
// 256 WGs (1/CU) x 256 thr. Weights fp16 in LDS (loaded once).
// R8: rotating write-once activation buffers (depth D, from ws_size) ->
// normal cached loads are coherent with NO per-step invalidation (drift
// between blocks is <=1 step << D); one buffer_inv per D steps at wrap.
// L2 now genuinely shares each broadcast line among the XCD's 32 blocks.
// FC distributed to all 256 blocks (8x redundant, tile = bid&31), fused
// into the h1-read that computes p1 -> no 32-block choke, min-of-8 y flag.
// Producers: sc1 write-through stores + vmcnt(0) + flag store. Polls:
// agent-scope atomic loads (L2-bypass). No atomics-RMW, no syncthreads.
// ---------------------------------------------------------------------------

#define NBLK 256
#define NTHR 256
#define HDIM 1024
#define ODIM 512
#define BDIM 64
#define SEQL 256

typedef _Float16 v8h __attribute__((ext_vector_type(8)));
typedef float    v4f __attribute__((ext_vector_type(4)));

// LDS: per k-slice, 64 lanes x 16B contiguous = 1024B (conflict-free b128)
#define WL0_NS 48                       // K = 512(y) + 1024(h0)
#define WL1_NS 64                       // K = 1024(h0) + 1024(h1)
#define WFC_NS 32                       // K = 1024
#define WL0_OFF 0
#define WL1_OFF (WL0_NS*1024)
#define WFC_OFF (WL1_OFF + WL1_NS*1024)
#define SMEM_BYTES (WFC_OFF + WFC_NS*1024)   // 147456 B

#define YB_SZ  (BDIM*ODIM*2)            // 64 KB per slot
#define HB_SZ  (BDIM*HDIM*2)            // 128 KB per slot
// flags: fh0[4][256], fh1[4][256], fy[4][32] uints, packed 4B
#define FH0_REL 0
#define FH1_REL (4*256*4)
#define FY_REL  (FH1_REL + 4*256*4)
#define FLG_BYTES (4*256*4 + 4*256*4 + 4*32*4)

__device__ __forceinline__ float fsig(float x)   { return 1.0f / (1.0f + __expf(-x)); }
__device__ __forceinline__ float ftanhf(float x) { return 1.0f - 2.0f / (__expf(2.0f*x) + 1.0f); }

// wrap-acquire: once per D steps — drop last-epoch clean lines.
__device__ __forceinline__ void wrap_inv(){
  asm volatile("s_waitcnt vmcnt(0)\n\tbuffer_inv sc1" ::: "memory");
}

// Wait on 256 packed flags (this row-group): lane polls flags [4*lane..4*lane+3].
__device__ __forceinline__ void wait_grp256(const unsigned int* rowf, unsigned int tag){
  const char* p = (const char*)(rowf + (threadIdx.x & 63)*4);
  while (true){
    unsigned long long a = __hip_atomic_load((const unsigned long long*)p,     __ATOMIC_RELAXED, __HIP_MEMORY_SCOPE_AGENT);
    unsigned long long b = __hip_atomic_load((const unsigned long long*)(p+8), __ATOMIC_RELAXED, __HIP_MEMORY_SCOPE_AGENT);
    unsigned int m0 = (unsigned int)a, m1 = (unsigned int)(a >> 32);
    unsigned int m2 = (unsigned int)b, m3 = (unsigned int)(b >> 32);
    unsigned int m = min(min(m0, m1), min(m2, m3));
    if (__all(m >= tag)) break;
    __builtin_amdgcn_s_sleep(4);
  }
  asm volatile("" ::: "memory");   // no hoisting data loads above the wait
}

// Wait on 32 packed flags: lane polls flag [lane&31].
__device__ __forceinline__ void wait_grp32(const unsigned int* rowf, unsigned int tag){
  const unsigned int* p = rowf + (threadIdx.x & 31);
  while (true){
    unsigned int v = __hip_atomic_load(p, __ATOMIC_RELAXED, __HIP_MEMORY_SCOPE_AGENT);
    if (__all(v >= tag)) break;
    __builtin_amdgcn_s_sleep(4);
  }
  asm volatile("" ::: "memory");
}

// Wave publish: drain this wave's vmem (sc1 data stores), store tag.
// Multiple redundant writers of the same tag are safe (identical data).
__device__ __forceinline__ void publish(unsigned int* flag, unsigned int tag){
  asm volatile("s_waitcnt vmcnt(0)" ::: "memory");
  if ((threadIdx.x & 63) == 0)
    __hip_atomic_store(flag, tag, __ATOMIC_RELAXED, __HIP_MEMORY_SCOPE_AGENT);
}

// K-loop: NC chunks of 256 K-cols (8 MFMAs each); A via normal cached loads.
template<int NC>
__device__ __forceinline__ v4f gemm_phase(const char* const cb[], const char* wl, v4f acc){
  v8h A[4][8];
  constexpr int PF = (NC < 3) ? NC : 3;
  #pragma unroll
  for (int p = 0; p < PF; p++){
    #pragma unroll
    for (int j = 0; j < 8; j++) A[p][j] = *(const v8h*)(cb[p] + (size_t)j*64);
  }
  #pragma unroll
  for (int c = 0; c < NC; c++){
    const int cur = c & 3, nx = (c + 3) & 3;
    if (c + 3 < NC){
      #pragma unroll
      for (int j = 0; j < 8; j++) A[nx][j] = *(const v8h*)(cb[c+3] + (size_t)j*64);
    }
    #pragma unroll
    for (int j = 0; j < 8; j++){
      v8h B = *(const v8h*)(wl + (size_t)(c*8 + j)*1024);
      acc = __builtin_amdgcn_mfma_f32_16x16x32_f16(A[cur][j], B, acc, 0, 0, 0);
    }
  }
  return acc;
}

// Same A-stream feeding two B matrices.
__device__ __forceinline__ void gemm_dual4(const char* const cb[], const char* wlA,
                                           const char* wlB, v4f& accA, v4f& accB){
  v8h A[4][8];
  #pragma unroll
  for (int p = 0; p < 3; p++){
    #pragma unroll
    for (int j = 0; j < 8; j++) A[p][j] = *(const v8h*)(cb[p] + (size_t)j*64);
  }
  #pragma unroll
  for (int c = 0; c < 4; c++){
    const int cur = c & 3, nx = (c + 3) & 3;
    if (c + 3 < 4){
      #pragma unroll
      for (int j = 0; j < 8; j++) A[nx][j] = *(const v8h*)(cb[c+3] + (size_t)j*64);
    }
    #pragma unroll
    for (int j = 0; j < 8; j++){
      v8h BA = *(const v8h*)(wlA + (size_t)(c*8 + j)*1024);
      accA = __builtin_amdgcn_mfma_f32_16x16x32_f16(A[cur][j], BA, accA, 0, 0, 0);
      v8h BB = *(const v8h*)(wlB + (size_t)(c*8 + j)*1024);
      accB = __builtin_amdgcn_mfma_f32_16x16x32_f16(A[cur][j], BB, accB, 0, 0, 0);
    }
  }
}

// LSTM epilogue: gate gather via xor1/2/3; h packed 4 units -> one 8B sc1 store.
__device__ __forceinline__ void lstm_epi_pack(v4f acc, float bias, float* cs,
                                              char* hbase, int l15, int gidx){
  #pragma unroll
  for (int r = 0; r < 4; r++){
    float v  = acc[r] + bias;
    float x1 = __shfl_xor(v, 1);
    float x2 = __shfl_xor(v, 2);
    float x3 = __shfl_xor(v, 3);
    float vi = (gidx==0)?v :(gidx==1)?x1:(gidx==2)?x2:x3;
    float vf = (gidx==1)?v :(gidx==0)?x1:(gidx==3)?x2:x3;
    float vg = (gidx==2)?v :(gidx==3)?x1:(gidx==0)?x2:x3;
    float vo = (gidx==3)?v :(gidx==2)?x1:(gidx==1)?x2:x3;
    float ii = fsig(vi), ff = fsig(vf), gg = ftanhf(vg), oo = fsig(vo);
    float cn = ff*cs[r] + ii*gg;
    cs[r] = cn;
    float hn = oo * ftanhf(cn);
    unsigned int uv = (unsigned int)__builtin_bit_cast(unsigned short, (_Float16)hn);
    unsigned int o4 = (unsigned int)__shfl_xor((int)uv, 4);
    unsigned int pr = uv | (o4 << 16);
    unsigned int o8 = (unsigned int)__shfl_xor((int)pr, 8);
    if (l15 == 0){
      unsigned long long full = (unsigned long long)pr | ((unsigned long long)o8 << 32);
      __hip_atomic_store((unsigned long long*)(hbase + (size_t)r*(HDIM*2)), full,
                         __ATOMIC_RELAXED, __HIP_MEMORY_SCOPE_AGENT);
    }
  }
}

__global__ void init_kernel(const float* __restrict__ h0,
                            _Float16* __restrict__ h0bi, _Float16* __restrict__ h1bi,
                            _Float16* __restrict__ ybi){
  int i = blockIdx.x*256 + threadIdx.x;
  if (i < BDIM*HDIM){
    h0bi[i] = (_Float16)h0[i];
    h1bi[i] = (_Float16)h0[BDIM*HDIM + i];
  }
  if (i < BDIM*ODIM) ybi[i] = (_Float16)(-2.0f); // SOS
}

__launch_bounds__(NTHR, 1)
__global__ void decoder_kernel(
    const float* __restrict__ Wih0, const float* __restrict__ Whh0,
    const float* __restrict__ bih0, const float* __restrict__ bhh0,
    const float* __restrict__ Wih1, const float* __restrict__ Whh1,
    const float* __restrict__ bih1, const float* __restrict__ bhh1,
    const float* __restrict__ Wfc,  const float* __restrict__ bfc,
    const float* __restrict__ c0in, float* __restrict__ out,
    char* __restrict__ yB, char* __restrict__ h0B, char* __restrict__ h1B,
    char* __restrict__ flg, int dmask)
{
  extern __shared__ char smem[];
  const int bid = blockIdx.x;
  const int tid = threadIdx.x;
  const int wv  = tid >> 6;
  const int ln  = tid & 63;
  const int l15 = ln & 15;
  const int lq  = ln >> 4;
  const int u0  = bid * 4;
  const int tile = bid & 31;           // FC tile (8x redundant writers)

  unsigned int* fh0r = (unsigned int*)(flg + FH0_REL) + wv*256;
  unsigned int* fh1r = (unsigned int*)(flg + FH1_REL) + wv*256;
  unsigned int* fyr  = (unsigned int*)(flg + FY_REL)  + wv*32;

  // ---- one-time: weights fp32->fp16 into LDS, exact fragment order ----
  for (int slot = tid; slot < WL0_NS*64; slot += NTHR){
    int s = slot >> 6, l = slot & 63;
    int r16 = l & 15, q = l >> 4;
    int grow = (r16 & 3)*HDIM + u0 + (r16 >> 2);
    int kb = s*32 + q*8;
    const float* src; int k0;
    if (kb < ODIM){ src = Wih0 + (size_t)grow*ODIM; k0 = kb; }
    else          { src = Whh0 + (size_t)grow*HDIM; k0 = kb - ODIM; }
    v8h hv;
    #pragma unroll
    for (int j = 0; j < 8; j++) hv[j] = (_Float16)src[k0 + j];
    *(v8h*)(smem + WL0_OFF + s*1024 + l*16) = hv;
  }
  for (int slot = tid; slot < WL1_NS*64; slot += NTHR){
    int s = slot >> 6, l = slot & 63;
    int r16 = l & 15, q = l >> 4;
    int grow = (r16 & 3)*HDIM + u0 + (r16 >> 2);
    int kb = s*32 + q*8;
    const float* src; int k0;
    if (kb < HDIM){ src = Wih1 + (size_t)grow*HDIM; k0 = kb; }
    else          { src = Whh1 + (size_t)grow*HDIM; k0 = kb - HDIM; }
    v8h hv;
    #pragma unroll
    for (int j = 0; j < 8; j++) hv[j] = (_Float16)src[k0 + j];
    *(v8h*)(smem + WL1_OFF + s*1024 + l*16) = hv;
  }
  for (int slot = tid; slot < WFC_NS*64; slot += NTHR){
    int s = slot >> 6, l = slot & 63;
    int r16 = l & 15, q = l >> 4;
    const float* src = Wfc + (size_t)(tile*16 + r16)*HDIM;
    int k0 = s*32 + q*8;
    v8h hv;
    #pragma unroll
    for (int j = 0; j < 8; j++) hv[j] = (_Float16)src[k0 + j];
    *(v8h*)(smem + WFC_OFF + s*1024 + l*16) = hv;
  }
  __syncthreads();   // LDS weights ready (only barrier in the kernel)

  // ---- per-lane constants ----
  const int gidx = l15 & 3;
  const int unit = u0 + (l15 >> 2);
  const int growL = gidx*HDIM + unit;
  const float bias0 = bih0[growL] + bhh0[growL];
  const float bias1 = bih1[growL] + bhh1[growL];
  const float biasf = bfc[tile*16 + l15];

  const int rb = wv*16 + lq*4;
  float cs0[4], cs1[4];
  #pragma unroll
  for (int r = 0; r < 4; r++){
    int b = rb + r;
    cs0[r] = c0in[(size_t)(0*BDIM + b)*HDIM + unit];
    cs1[r] = c0in[(size_t)(1*BDIM + b)*HDIM + unit];
  }

  const int row = wv*16 + l15;
  const size_t aoffY = (size_t)row*ODIM*2 + (size_t)lq*16;
  const size_t aoffH = (size_t)row*HDIM*2 + (size_t)lq*16;
  const size_t hwoff = ((size_t)rb*HDIM + u0)*2;   // h-store base (l15==0 lanes)
  const char* wl0 = smem + WL0_OFF + ln*16;
  const char* wl1 = smem + WL1_OFF + ln*16;
  const char* wlf = smem + WFC_OFF + ln*16;
  const char* wl0r = wl0 + 16*1024;   // Whh0 slices
  const char* wl1r = wl1 + 32*1024;   // Whh1 slices

  // prologue: p0 = Whh0 @ h0_init (slot dmask; init kernel flushed at boundary)
  v4f p0 = {0.f,0.f,0.f,0.f};
  {
    const char* hi = h0B + (size_t)dmask*HB_SZ + aoffH;
    const char* cb[4] = { hi, hi+512, hi+1024, hi+1536 };
    p0 = gemm_phase<4>(cb, wl0r, p0);
  }

  for (int t = 0; t <= SEQL; t++){
    const int sp = (t - 1) & dmask;    // prev-step slot ((-1)&dmask == dmask)
    const int sc = t & dmask;          // cur-step slot

    if ((t & dmask) == 0) wrap_inv();  // once per rotation epoch

    // -- 1: h1[t-1] ready?
    if (t > 0) wait_grp256(fh1r, (unsigned)t);

    // -- 2: read h1[t-1] once: p1 = Whh1@h1  AND  yfc = FC-tile(h1)
    v4f p1 = {0.f,0.f,0.f,0.f};
    {
      const char* hs = h1B + (size_t)sp*HB_SZ + aoffH;
      const char* cb[4] = { hs, hs+512, hs+1024, hs+1536 };
      v4f yfc = {0.f,0.f,0.f,0.f};
      gemm_dual4(cb, wl1r, wlf, p1, yfc);
      if (t > 0){
        char* ydst = yB + (size_t)sp*YB_SZ;
        #pragma unroll
        for (int r = 0; r < 4; r++){
          float v = fmaxf(yfc[r] + biasf, 0.f);
          int b = rb + r;
          int o = tile*16 + l15;
          out[((size_t)b*SEQL + (t-1))*ODIM + o] = v;   // 8x dup, identical
          if (t < SEQL){
            unsigned int uv = (unsigned int)__builtin_bit_cast(unsigned short, (_Float16)v);
            unsigned int o1 = (unsigned int)__shfl_xor((int)uv, 1);
            unsigned int pr = uv | (o1 << 16);
            unsigned int o2 = (unsigned int)__shfl_xor((int)pr, 2);
            if ((l15 & 3) == 0){
              unsigned long long full = (unsigned long long)pr | ((unsigned long long)o2 << 32);
              __hip_atomic_store((unsigned long long*)(ydst + ((size_t)b*ODIM + o)*2),
                                 full, __ATOMIC_RELAXED, __HIP_MEMORY_SCOPE_AGENT);
            }
          }
        }
        if (t < SEQL) publish(&fyr[tile], (unsigned)t);
      }
    }
    if (t == SEQL) break;

    // -- 3: y[t-1] ready? (32 tiles, min-of-8-writers each)
    if (t > 0) wait_grp32(fyr, (unsigned)t);

    // -- 4: L0 input part (K=512) + recurrent partial -> h0[t]
    {
      const char* ysrc = yB + (size_t)sp*YB_SZ + aoffY;
      const char* cb[2] = { ysrc, ysrc+512 };
      v4f acc = gemm_phase<2>(cb, wl0, p0);
      lstm_epi_pack(acc, bias0, cs0, h0B + (size_t)sc*HB_SZ + hwoff, l15, gidx);
    }
    publish(&fh0r[bid], (unsigned)(t+1));

    // -- 5: h0[t] (rows of this wv, all blocks) ready?
    wait_grp256(fh0r, (unsigned)(t+1));

    // -- 6: L1 input part + fused next-step L0 recurrent (shared A) -> h1[t]
    {
      const char* hs = h0B + (size_t)sc*HB_SZ + aoffH;
      const char* cb[4] = { hs, hs+512, hs+1024, hs+1536 };
      v4f np0 = {0.f,0.f,0.f,0.f};
      gemm_dual4(cb, wl1, wl0r, p1, np0);
      lstm_epi_pack(p1, bias1, cs1, h1B + (size_t)sc*HB_SZ + hwoff, l15, gidx);
      p0 = np0;
    }
    publish(&fh1r[bid], (unsigned)(t+1));
  }
}

extern "C" void kernel_launch(void* const* d_in, const int* in_sizes, int n_in,
                              void* d_out, int out_size, void* d_ws, size_t ws_size,
                              hipStream_t stream){
  (void)in_sizes; (void)n_in; (void)out_size;

  // choose rotation depth D (pow2) from ws_size
  int D = 16;
  while (D > 2 && (size_t)D*(YB_SZ + 2*HB_SZ) + FLG_BYTES > ws_size) D >>= 1;
  if ((size_t)D*(YB_SZ + 2*HB_SZ) + FLG_BYTES > ws_size) return;

  char* ws  = (char*)d_ws;
  char* yB  = ws;
  char* h0B = yB + (size_t)D*YB_SZ;
  char* h1B = h0B + (size_t)D*HB_SZ;
  char* flg = h1B + (size_t)D*HB_SZ;

  const float* h0   = (const float*)d_in[1];
  const float* c0   = (const float*)d_in[2];
  const float* Wih0 = (const float*)d_in[3];
  const float* Whh0 = (const float*)d_in[4];
  const float* bih0 = (const float*)d_in[5];
  const float* bhh0 = (const float*)d_in[6];
  const float* Wih1 = (const float*)d_in[7];
  const float* Whh1 = (const float*)d_in[8];
  const float* bih1 = (const float*)d_in[9];
  const float* bhh1 = (const float*)d_in[10];
  const float* Wfc  = (const float*)d_in[11];
  const float* bfc  = (const float*)d_in[12];
  float* out = (float*)d_out;

  (void)hipMemsetAsync(flg, 0, FLG_BYTES, stream);
  hipLaunchKernelGGL(init_kernel, dim3(256), dim3(256), 0, stream,
                     h0,
                     (_Float16*)(h0B + (size_t)(D-1)*HB_SZ),
                     (_Float16*)(h1B + (size_t)(D-1)*HB_SZ),
                     (_Float16*)(yB  + (size_t)(D-1)*YB_SZ));

  (void)hipFuncSetAttribute((const void*)decoder_kernel,
                            hipFuncAttributeMaxDynamicSharedMemorySize, SMEM_BYTES);
  hipLaunchKernelGGL(decoder_kernel, dim3(NBLK), dim3(NTHR), SMEM_BYTES, stream,
                     Wih0, Whh0, bih0, bhh0, Wih1, Whh1, bih1, bhh1,
                     Wfc, bfc, c0, out, yB, h0B, h1B, flg, D - 1);
}

// Round 9
// 5431.178 us; speedup vs baseline: 2.2938x; 2.2938x over previous
//
#include <hip/hip_runtime.h>
#include <stdint.h>

// ---------------------------------------------------------------------------
// Persistent-RNN 2-layer LSTM decoder (B=64,H=1024,OUT=512,SEQ=256), MI355X.
// R9 = best-of-all-rounds combination:
//  * R7 3-wait schedule, FC on 32 blocks only (off 224 blocks' critical path)
//  * R8 rotating write-once activation buffers (depth D) -> normal cached
//    16B loads are coherent with NO per-step invalidation; buffer_inv only
//    once per D steps. L2 shares each broadcast line across the XCD.
//  * NEW: XCD-leader-aggregated waits. Leader block (bid<8) scans the flag
//    row (its wait anyway), then stores one epoch word per (wv, xcd);
//    followers poll a single word. ~30x poll-traffic cut. Store-only flags
//    (single writer/word), no RMW (R5 lesson), no __syncthreads in loop.
// ---------------------------------------------------------------------------

#define NBLK 256
#define NTHR 256
#define HDIM 1024
#define ODIM 512
#define BDIM 64
#define SEQL 256

typedef _Float16 v8h __attribute__((ext_vector_type(8)));
typedef float    v4f __attribute__((ext_vector_type(4)));

// LDS: per k-slice, 64 lanes x 16B contiguous = 1024B (conflict-free b128)
#define WL0_NS 48                       // K = 512(y) + 1024(h0)
#define WL1_NS 64                       // K = 1024(h0) + 1024(h1)
#define WFC_NS 32                       // K = 1024
#define WL0_OFF 0
#define WL1_OFF (WL0_NS*1024)
#define WFC_OFF (WL1_OFF + WL1_NS*1024)
#define SMEM_BYTES (WFC_OFF + WFC_NS*1024)   // 147456 B

#define YB_SZ  (BDIM*ODIM*2)            // 64 KB per slot
#define HB_SZ  (BDIM*HDIM*2)            // 128 KB per slot

// flag region layout (relative):
// fh0[4][256], fh1[4][256], fy[4][32] uints packed 4B;
// epochs: eh0[4][8], ey[4][8] words, 64B stride each.
#define FH0_REL 0
#define FH1_REL (4*256*4)
#define FY_REL  (FH1_REL + 4*256*4)
#define EH0_REL (FY_REL + 4*32*4)
#define EY_REL  (EH0_REL + 4*8*64)
#define FLG_BYTES (EY_REL + 4*8*64)

__device__ __forceinline__ float fsig(float x)   { return 1.0f / (1.0f + __expf(-x)); }
__device__ __forceinline__ float ftanhf(float x) { return 1.0f - 2.0f / (__expf(2.0f*x) + 1.0f); }

__device__ __forceinline__ unsigned long long ald8(const void* p){
  return __hip_atomic_load((const unsigned long long*)p, __ATOMIC_RELAXED, __HIP_MEMORY_SCOPE_AGENT);
}
__device__ __forceinline__ unsigned int ald4(const void* p){
  return __hip_atomic_load((const unsigned int*)p, __ATOMIC_RELAXED, __HIP_MEMORY_SCOPE_AGENT);
}
__device__ __forceinline__ void ast4(void* p, unsigned int v){
  __hip_atomic_store((unsigned int*)p, v, __ATOMIC_RELAXED, __HIP_MEMORY_SCOPE_AGENT);
}

// wrap-acquire: once per D steps — drop last-epoch clean L2 lines.
__device__ __forceinline__ void wrap_inv(){
  asm volatile("s_waitcnt vmcnt(0)\n\tbuffer_inv sc1" ::: "memory");
}

// Leader: scan 256 packed flags (this row-group) until all >= tag, then store
// epoch word. Follower: poll the single epoch word.
__device__ __forceinline__ void wait_h_agg(const unsigned int* rowf, unsigned int* ep,
                                           int leader, unsigned int tag){
  if (leader){
    const char* p = (const char*)(rowf + (threadIdx.x & 63)*4);
    while (true){
      unsigned long long a = ald8(p);
      unsigned long long b = ald8(p+8);
      unsigned int m0 = (unsigned int)a, m1 = (unsigned int)(a >> 32);
      unsigned int m2 = (unsigned int)b, m3 = (unsigned int)(b >> 32);
      unsigned int m = min(min(m0, m1), min(m2, m3));
      if (__all(m >= tag)) break;
      __builtin_amdgcn_s_sleep(2);
    }
    if ((threadIdx.x & 63) == 0) ast4(ep, tag);
  } else {
    while (ald4(ep) < tag) __builtin_amdgcn_s_sleep(2);
  }
  asm volatile("" ::: "memory");
}

// Leader: scan 32 packed flags; follower: poll epoch word.
__device__ __forceinline__ void wait_y_agg(const unsigned int* rowf, unsigned int* ep,
                                           int leader, unsigned int tag){
  if (leader){
    const unsigned int* p = rowf + (threadIdx.x & 31);
    while (true){
      unsigned int v = ald4(p);
      if (__all(v >= tag)) break;
      __builtin_amdgcn_s_sleep(2);
    }
    if ((threadIdx.x & 63) == 0) ast4(ep, tag);
  } else {
    while (ald4(ep) < tag) __builtin_amdgcn_s_sleep(2);
  }
  asm volatile("" ::: "memory");
}

// Direct scan of 256 flags (used only by the 32 FC blocks).
__device__ __forceinline__ void wait_grp256(const unsigned int* rowf, unsigned int tag){
  const char* p = (const char*)(rowf + (threadIdx.x & 63)*4);
  while (true){
    unsigned long long a = ald8(p);
    unsigned long long b = ald8(p+8);
    unsigned int m0 = (unsigned int)a, m1 = (unsigned int)(a >> 32);
    unsigned int m2 = (unsigned int)b, m3 = (unsigned int)(b >> 32);
    unsigned int m = min(min(m0, m1), min(m2, m3));
    if (__all(m >= tag)) break;
    __builtin_amdgcn_s_sleep(2);
  }
  asm volatile("" ::: "memory");
}

// Wave publish: drain this wave's vmem (reads+writes), store tag (1 writer).
__device__ __forceinline__ void publish(unsigned int* flag, unsigned int tag){
  asm volatile("s_waitcnt vmcnt(0)" ::: "memory");
  if ((threadIdx.x & 63) == 0) ast4(flag, tag);
}

// K-loop: NC chunks of 256 K-cols (8 MFMAs each); A via normal cached loads.
template<int NC>
__device__ __forceinline__ v4f gemm_phase(const char* const cb[], const char* wl, v4f acc){
  v8h A[4][8];
  constexpr int PF = (NC < 3) ? NC : 3;
  #pragma unroll
  for (int p = 0; p < PF; p++){
    #pragma unroll
    for (int j = 0; j < 8; j++) A[p][j] = *(const v8h*)(cb[p] + (size_t)j*64);
  }
  #pragma unroll
  for (int c = 0; c < NC; c++){
    const int cur = c & 3, nx = (c + 3) & 3;
    if (c + 3 < NC){
      #pragma unroll
      for (int j = 0; j < 8; j++) A[nx][j] = *(const v8h*)(cb[c+3] + (size_t)j*64);
    }
    #pragma unroll
    for (int j = 0; j < 8; j++){
      v8h B = *(const v8h*)(wl + (size_t)(c*8 + j)*1024);
      acc = __builtin_amdgcn_mfma_f32_16x16x32_f16(A[cur][j], B, acc, 0, 0, 0);
    }
  }
  return acc;
}

// Same A-stream feeding two B matrices (L1 input-part + next-step L0 recurrent).
__device__ __forceinline__ void gemm_dual4(const char* const cb[], const char* wlA,
                                           const char* wlB, v4f& accA, v4f& accB){
  v8h A[4][8];
  #pragma unroll
  for (int p = 0; p < 3; p++){
    #pragma unroll
    for (int j = 0; j < 8; j++) A[p][j] = *(const v8h*)(cb[p] + (size_t)j*64);
  }
  #pragma unroll
  for (int c = 0; c < 4; c++){
    const int cur = c & 3, nx = (c + 3) & 3;
    if (c + 3 < 4){
      #pragma unroll
      for (int j = 0; j < 8; j++) A[nx][j] = *(const v8h*)(cb[c+3] + (size_t)j*64);
    }
    #pragma unroll
    for (int j = 0; j < 8; j++){
      v8h BA = *(const v8h*)(wlA + (size_t)(c*8 + j)*1024);
      accA = __builtin_amdgcn_mfma_f32_16x16x32_f16(A[cur][j], BA, accA, 0, 0, 0);
      v8h BB = *(const v8h*)(wlB + (size_t)(c*8 + j)*1024);
      accB = __builtin_amdgcn_mfma_f32_16x16x32_f16(A[cur][j], BB, accB, 0, 0, 0);
    }
  }
}

// LSTM epilogue: gate gather via xor1/2/3; h packed 4 units -> one 8B sc1 store.
__device__ __forceinline__ void lstm_epi_pack(v4f acc, float bias, float* cs,
                                              char* hbase, int l15, int gidx){
  #pragma unroll
  for (int r = 0; r < 4; r++){
    float v  = acc[r] + bias;
    float x1 = __shfl_xor(v, 1);
    float x2 = __shfl_xor(v, 2);
    float x3 = __shfl_xor(v, 3);
    float vi = (gidx==0)?v :(gidx==1)?x1:(gidx==2)?x2:x3;
    float vf = (gidx==1)?v :(gidx==0)?x1:(gidx==3)?x2:x3;
    float vg = (gidx==2)?v :(gidx==3)?x1:(gidx==0)?x2:x3;
    float vo = (gidx==3)?v :(gidx==2)?x1:(gidx==1)?x2:x3;
    float ii = fsig(vi), ff = fsig(vf), gg = ftanhf(vg), oo = fsig(vo);
    float cn = ff*cs[r] + ii*gg;
    cs[r] = cn;
    float hn = oo * ftanhf(cn);
    unsigned int uv = (unsigned int)__builtin_bit_cast(unsigned short, (_Float16)hn);
    unsigned int o4 = (unsigned int)__shfl_xor((int)uv, 4);
    unsigned int pr = uv | (o4 << 16);
    unsigned int o8 = (unsigned int)__shfl_xor((int)pr, 8);
    if (l15 == 0){
      unsigned long long full = (unsigned long long)pr | ((unsigned long long)o8 << 32);
      __hip_atomic_store((unsigned long long*)(hbase + (size_t)r*(HDIM*2)), full,
                         __ATOMIC_RELAXED, __HIP_MEMORY_SCOPE_AGENT);
    }
  }
}

__global__ void init_kernel(const float* __restrict__ h0,
                            _Float16* __restrict__ h0bi, _Float16* __restrict__ h1bi,
                            _Float16* __restrict__ ybi){
  int i = blockIdx.x*256 + threadIdx.x;
  if (i < BDIM*HDIM){
    h0bi[i] = (_Float16)h0[i];
    h1bi[i] = (_Float16)h0[BDIM*HDIM + i];
  }
  if (i < BDIM*ODIM) ybi[i] = (_Float16)(-2.0f); // SOS
}

__launch_bounds__(NTHR, 1)
__global__ void decoder_kernel(
    const float* __restrict__ Wih0, const float* __restrict__ Whh0,
    const float* __restrict__ bih0, const float* __restrict__ bhh0,
    const float* __restrict__ Wih1, const float* __restrict__ Whh1,
    const float* __restrict__ bih1, const float* __restrict__ bhh1,
    const float* __restrict__ Wfc,  const float* __restrict__ bfc,
    const float* __restrict__ c0in, float* __restrict__ out,
    char* __restrict__ yB, char* __restrict__ h0B, char* __restrict__ h1B,
    char* __restrict__ flg, int dmask)
{
  extern __shared__ char smem[];
  const int bid = blockIdx.x;
  const int tid = threadIdx.x;
  const int wv  = tid >> 6;
  const int ln  = tid & 63;
  const int l15 = ln & 15;
  const int lq  = ln >> 4;
  const int u0  = bid * 4;
  const int xcd = bid & 7;
  const int leader = (bid < 8);

  unsigned int* fh0r = (unsigned int*)(flg + FH0_REL) + wv*256;
  unsigned int* fh1r = (unsigned int*)(flg + FH1_REL) + wv*256;
  unsigned int* fyr  = (unsigned int*)(flg + FY_REL)  + wv*32;
  unsigned int* eh0  = (unsigned int*)(flg + EH0_REL + (wv*8 + xcd)*64);
  unsigned int* ey   = (unsigned int*)(flg + EY_REL  + (wv*8 + xcd)*64);

  // ---- one-time: weights fp32->fp16 into LDS, exact fragment order ----
  for (int slot = tid; slot < WL0_NS*64; slot += NTHR){
    int s = slot >> 6, l = slot & 63;
    int r16 = l & 15, q = l >> 4;
    int grow = (r16 & 3)*HDIM + u0 + (r16 >> 2);
    int kb = s*32 + q*8;
    const float* src; int k0;
    if (kb < ODIM){ src = Wih0 + (size_t)grow*ODIM; k0 = kb; }
    else          { src = Whh0 + (size_t)grow*HDIM; k0 = kb - ODIM; }
    v8h hv;
    #pragma unroll
    for (int j = 0; j < 8; j++) hv[j] = (_Float16)src[k0 + j];
    *(v8h*)(smem + WL0_OFF + s*1024 + l*16) = hv;
  }
  for (int slot = tid; slot < WL1_NS*64; slot += NTHR){
    int s = slot >> 6, l = slot & 63;
    int r16 = l & 15, q = l >> 4;
    int grow = (r16 & 3)*HDIM + u0 + (r16 >> 2);
    int kb = s*32 + q*8;
    const float* src; int k0;
    if (kb < HDIM){ src = Wih1 + (size_t)grow*HDIM; k0 = kb; }
    else          { src = Whh1 + (size_t)grow*HDIM; k0 = kb - HDIM; }
    v8h hv;
    #pragma unroll
    for (int j = 0; j < 8; j++) hv[j] = (_Float16)src[k0 + j];
    *(v8h*)(smem + WL1_OFF + s*1024 + l*16) = hv;
  }
  if (bid < 32){
    for (int slot = tid; slot < WFC_NS*64; slot += NTHR){
      int s = slot >> 6, l = slot & 63;
      int r16 = l & 15, q = l >> 4;
      const float* src = Wfc + (size_t)(bid*16 + r16)*HDIM;
      int k0 = s*32 + q*8;
      v8h hv;
      #pragma unroll
      for (int j = 0; j < 8; j++) hv[j] = (_Float16)src[k0 + j];
      *(v8h*)(smem + WFC_OFF + s*1024 + l*16) = hv;
    }
  }
  __syncthreads();   // LDS weights ready (only barrier in the kernel)

  // ---- per-lane constants ----
  const int gidx = l15 & 3;
  const int unit = u0 + (l15 >> 2);
  const int growL = gidx*HDIM + unit;
  const float bias0 = bih0[growL] + bhh0[growL];
  const float bias1 = bih1[growL] + bhh1[growL];
  float biasf = 0.f;
  if (bid < 32) biasf = bfc[bid*16 + l15];

  const int rb = wv*16 + lq*4;
  float cs0[4], cs1[4];
  #pragma unroll
  for (int r = 0; r < 4; r++){
    int b = rb + r;
    cs0[r] = c0in[(size_t)(0*BDIM + b)*HDIM + unit];
    cs1[r] = c0in[(size_t)(1*BDIM + b)*HDIM + unit];
  }

  const int row = wv*16 + l15;
  const size_t aoffY = (size_t)row*ODIM*2 + (size_t)lq*16;
  const size_t aoffH = (size_t)row*HDIM*2 + (size_t)lq*16;
  const size_t hwoff = ((size_t)rb*HDIM + u0)*2;   // h-store base (l15==0 lanes)
  const char* wl0 = smem + WL0_OFF + ln*16;
  const char* wl1 = smem + WL1_OFF + ln*16;
  const char* wlf = smem + WFC_OFF + ln*16;
  const char* wl0r = wl0 + 16*1024;   // Whh0 slices
  const char* wl1r = wl1 + 32*1024;   // Whh1 slices

  // prologue: p0 = Whh0 @ h0_init (slot dmask; init kernel flushed at boundary)
  v4f p0 = {0.f,0.f,0.f,0.f};
  {
    const char* hi = h0B + (size_t)dmask*HB_SZ + aoffH;
    const char* cb[4] = { hi, hi+512, hi+1024, hi+1536 };
    p0 = gemm_phase<4>(cb, wl0r, p0);
  }

  for (int t = 0; t < SEQL; t++){
    const int sp = (t - 1) & dmask;    // prev-step slot ((-1)&dmask == dmask)
    const int sc = t & dmask;          // cur-step slot

    if ((t & dmask) == 0) wrap_inv();  // once per rotation epoch

    // -- 1: y[t-1] ready? (leader-aggregated; implies fh1[t-1] transitively)
    if (t > 0) wait_y_agg(fyr, ey, leader, (unsigned)t);

    // -- 2: L0 input part (K=512) + recurrent partial -> h0[t]
    {
      const char* ysrc = yB + (size_t)sp*YB_SZ + aoffY;
      const char* cb[2] = { ysrc, ysrc+512 };
      v4f acc = gemm_phase<2>(cb, wl0, p0);
      lstm_epi_pack(acc, bias0, cs0, h0B + (size_t)sc*HB_SZ + hwoff, l15, gidx);
    }
    publish(&fh0r[bid], (unsigned)(t+1));

    // -- 3 (off critical path): p1 = Whh1 @ h1[t-1]  (covered by fy wait)
    v4f p1 = {0.f,0.f,0.f,0.f};
    {
      const char* hs = h1B + (size_t)sp*HB_SZ + aoffH;
      const char* cb[4] = { hs, hs+512, hs+1024, hs+1536 };
      p1 = gemm_phase<4>(cb, wl1r, p1);
    }

    // -- 4: h0[t] ready? (leader-aggregated)
    wait_h_agg(fh0r, eh0, leader, (unsigned)(t+1));

    // -- 5: L1 input part + fused next-step L0 recurrent (shared A) -> h1[t]
    {
      const char* hs = h0B + (size_t)sc*HB_SZ + aoffH;
      const char* cb[4] = { hs, hs+512, hs+1024, hs+1536 };
      v4f np0 = {0.f,0.f,0.f,0.f};
      gemm_dual4(cb, wl1, wl0r, p1, np0);
      lstm_epi_pack(p1, bias1, cs1, h1B + (size_t)sc*HB_SZ + hwoff, l15, gidx);
      p0 = np0;
    }
    publish(&fh1r[bid], (unsigned)(t+1));

    // -- 6 (blocks 0..31): FC -> out[:,t], y[t]
    if (bid < 32){
      wait_grp256(fh1r, (unsigned)(t+1));
      const char* f = h1B + (size_t)sc*HB_SZ + aoffH;
      const char* cb[4] = { f, f+512, f+1024, f+1536 };
      v4f acc = {0.f,0.f,0.f,0.f};
      acc = gemm_phase<4>(cb, wlf, acc);
      char* ydst = yB + (size_t)sc*YB_SZ;
      #pragma unroll
      for (int r = 0; r < 4; r++){
        float v = fmaxf(acc[r] + biasf, 0.f);
        int b = rb + r;
        int o = bid*16 + l15;
        out[((size_t)b*SEQL + t)*ODIM + o] = v;
        unsigned int uv = (unsigned int)__builtin_bit_cast(unsigned short, (_Float16)v);
        unsigned int o1 = (unsigned int)__shfl_xor((int)uv, 1);
        unsigned int pr = uv | (o1 << 16);
        unsigned int o2 = (unsigned int)__shfl_xor((int)pr, 2);
        if ((l15 & 3) == 0){
          unsigned long long full = (unsigned long long)pr | ((unsigned long long)o2 << 32);
          __hip_atomic_store((unsigned long long*)(ydst + ((size_t)b*ODIM + o)*2),
                             full, __ATOMIC_RELAXED, __HIP_MEMORY_SCOPE_AGENT);
        }
      }
      publish(&fyr[bid], (unsigned)(t+1));
    }
  }
}

extern "C" void kernel_launch(void* const* d_in, const int* in_sizes, int n_in,
                              void* d_out, int out_size, void* d_ws, size_t ws_size,
                              hipStream_t stream){
  (void)in_sizes; (void)n_in; (void)out_size;

  // rotation depth D (pow2) from ws_size
  int D = 16;
  while (D > 2 && (size_t)D*(YB_SZ + 2*HB_SZ) + FLG_BYTES > ws_size) D >>= 1;
  if ((size_t)D*(YB_SZ + 2*HB_SZ) + FLG_BYTES > ws_size) return;

  char* ws  = (char*)d_ws;
  char* yB  = ws;
  char* h0B = yB + (size_t)D*YB_SZ;
  char* h1B = h0B + (size_t)D*HB_SZ;
  char* flg = h1B + (size_t)D*HB_SZ;

  const float* h0   = (const float*)d_in[1];
  const float* c0   = (const float*)d_in[2];
  const float* Wih0 = (const float*)d_in[3];
  const float* Whh0 = (const float*)d_in[4];
  const float* bih0 = (const float*)d_in[5];
  const float* bhh0 = (const float*)d_in[6];
  const float* Wih1 = (const float*)d_in[7];
  const float* Whh1 = (const float*)d_in[8];
  const float* bih1 = (const float*)d_in[9];
  const float* bhh1 = (const float*)d_in[10];
  const float* Wfc  = (const float*)d_in[11];
  const float* bfc  = (const float*)d_in[12];
  float* out = (float*)d_out;

  (void)hipMemsetAsync(flg, 0, FLG_BYTES, stream);
  hipLaunchKernelGGL(init_kernel, dim3(256), dim3(256), 0, stream,
                     h0,
                     (_Float16*)(h0B + (size_t)(D-1)*HB_SZ),
                     (_Float16*)(h1B + (size_t)(D-1)*HB_SZ),
                     (_Float16*)(yB  + (size_t)(D-1)*YB_SZ));

  (void)hipFuncSetAttribute((const void*)decoder_kernel,
                            hipFuncAttributeMaxDynamicSharedMemorySize, SMEM_BYTES);
  hipLaunchKernelGGL(decoder_kernel, dim3(NBLK), dim3(NTHR), SMEM_BYTES, stream,
                     Wih0, Whh0, bih0, bhh0, Wih1, Whh1, bih1, bhh1,
                     Wfc, bfc, c0, out, yB, h0B, h1B, flg, D - 1);
}